// Round 1
// baseline (409.021 us; speedup 1.0000x reference)
//
#include <hip/hip_runtime.h>
#include <stdint.h>

// ---------------------------------------------------------------------------
// PerformerAttention on MI355X (gfx950), bf16 MFMA pipeline.
// B=2 S=2048 D=512 H=8 dh=64.
//   k1 convert: f32 -> bf16 (x, Wq|Wk|Wv concat, Wo)
//   k2 qkv_gemm: [4096x512] @ [1536x512]^T + bias, relu(Q,K); V written transposed
//   k3 ksum: rq[n,h] = 1/(sum_d relu(k) + eps)
//   k4 attn: per (b,h), 64 q-rows/block; 2-pass softmax, attn -> d_out, O=P@V
//   k5 proj_gemm: O @ Wo^T + bo -> d_out
// ---------------------------------------------------------------------------

typedef __attribute__((ext_vector_type(8))) short short8;  // 8 x bf16 (guide-verified operand type)
typedef __attribute__((ext_vector_type(4))) float f4;

#define MFMA(a, b, c) __builtin_amdgcn_mfma_f32_16x16x32_bf16(a, b, c, 0, 0, 0)

struct __align__(8) us4 { uint16_t a, b, c, d; };

__device__ __forceinline__ uint16_t f2bf(float f) {
  union { float f; uint32_t u; } v; v.f = f;
  uint32_t u = v.u;
  return (uint16_t)((u + 0x7fffu + ((u >> 16) & 1u)) >> 16);  // RNE
}
__device__ __forceinline__ float bf2f(uint16_t u) {
  union { uint32_t u; float f; } v; v.u = ((uint32_t)u) << 16; return v.f;
}
__device__ __forceinline__ us4 pack4(float4 v) {
  us4 r; r.a = f2bf(v.x); r.b = f2bf(v.y); r.c = f2bf(v.z); r.d = f2bf(v.w); return r;
}

// async global->LDS, 16B/lane. LDS dest = wave-uniform base + lane*16.
__device__ __forceinline__ void async16(const uint16_t* g, uint16_t* l) {
  __builtin_amdgcn_global_load_lds(
      (const __attribute__((address_space(1))) void*)g,
      (__attribute__((address_space(3))) void*)l, 16, 0, 0);
}

// ---------------------------------------------------------------------------
__global__ __launch_bounds__(256) void convert_kernel(
    const float* __restrict__ x, const float* __restrict__ Wq,
    const float* __restrict__ Wk, const float* __restrict__ Wv,
    const float* __restrict__ Wo, uint16_t* __restrict__ xb,
    uint16_t* __restrict__ W3, uint16_t* __restrict__ Wob) {
  int i = blockIdx.x * 256 + threadIdx.x;           // 0..524287, 4 elems each
  ((us4*)xb)[i] = pack4(((const float4*)x)[i]);
  if (i < 65536) {                                  // 262144 elems per weight
    ((us4*)W3)[i]           = pack4(((const float4*)Wq)[i]);
    ((us4*)W3)[65536 + i]   = pack4(((const float4*)Wk)[i]);
    ((us4*)W3)[131072 + i]  = pack4(((const float4*)Wv)[i]);
    ((us4*)Wob)[i]          = pack4(((const float4*)Wo)[i]);
  }
}

// ---------------------------------------------------------------------------
// Shared 128x128 bf16 gemm_bt mainloop: C[row,col] = sum_k A[row,k]*Bt[col,k].
// lda = ldb = K = 512 for every GEMM in this problem.
__device__ __forceinline__ void gemm_loop(
    const uint16_t* __restrict__ A, const uint16_t* __restrict__ Bt,
    int row0, int col0, uint16_t* Alds, uint16_t* Blds, f4 (&acc)[4][4]) {
  const int tid = threadIdx.x;
  const int w = tid >> 6, lane = tid & 63;
  const int c = lane & 15, quad = lane >> 4;
  const int wm = w >> 1, wn = w & 1;
  const int srow = lane >> 2, scol = (lane & 3) * 8;   // 1KB chunk: 16 rows x 64B
  const uint16_t* Asrc = A + (size_t)(row0 + srow) * 512 + scol;
  const uint16_t* Bsrc = Bt + (size_t)(col0 + srow) * 512 + scol;
  for (int k0 = 0; k0 < 512; k0 += 32) {
    __syncthreads();
#pragma unroll
    for (int chh = 0; chh < 2; ++chh) {
      int ch = w * 2 + chh;                            // 8 chunks, 2 per wave
      async16(Asrc + (size_t)ch * 16 * 512 + k0, Alds + ch * 512);
      async16(Bsrc + (size_t)ch * 16 * 512 + k0, Blds + ch * 512);
    }
    __syncthreads();                                   // drains vmcnt
    short8 af[4], bf[4];
#pragma unroll
    for (int mi = 0; mi < 4; ++mi)
      af[mi] = *(const short8*)&Alds[(wm * 64 + mi * 16 + c) * 32 + quad * 8];
#pragma unroll
    for (int ni = 0; ni < 4; ++ni)
      bf[ni] = *(const short8*)&Blds[(wn * 64 + ni * 16 + c) * 32 + quad * 8];
#pragma unroll
    for (int mi = 0; mi < 4; ++mi)
#pragma unroll
      for (int ni = 0; ni < 4; ++ni)
        acc[mi][ni] = MFMA(af[mi], bf[ni], acc[mi][ni]);
  }
}

// ---------------------------------------------------------------------------
__global__ __launch_bounds__(256) void qkv_gemm(
    const uint16_t* __restrict__ xb, const uint16_t* __restrict__ W3,
    const float* __restrict__ bq, const float* __restrict__ bk,
    const float* __restrict__ bv, uint16_t* __restrict__ Qb,
    uint16_t* __restrict__ Kb, uint16_t* __restrict__ Vt) {
  __shared__ __align__(16) uint16_t Alds[128 * 32];
  __shared__ __align__(16) uint16_t Blds[128 * 32];
  f4 acc[4][4] = {};
  const int row0 = blockIdx.y * 128, col0 = blockIdx.x * 128;
  gemm_loop(xb, W3, row0, col0, Alds, Blds, acc);
  const int tid = threadIdx.x, w = tid >> 6, lane = tid & 63;
  const int c = lane & 15, quad = lane >> 4;
  const int wm = w >> 1, wn = w & 1;
  const int r3 = col0 >> 9;                        // 0=Q, 1=K, 2=V (block-uniform)
  const float* bias = (r3 == 0) ? bq : (r3 == 1) ? bk : bv;
#pragma unroll
  for (int mi = 0; mi < 4; ++mi)
#pragma unroll
    for (int ni = 0; ni < 4; ++ni)
#pragma unroll
      for (int r = 0; r < 4; ++r) {
        int row = row0 + wm * 64 + mi * 16 + quad * 4 + r;
        int col = col0 + wn * 64 + ni * 16 + c;
        int o = col & 511;
        float v = acc[mi][ni][r] + bias[o];
        if (r3 == 0) {
          Qb[(size_t)row * 512 + o] = f2bf(fmaxf(v, 0.0f));
        } else if (r3 == 1) {
          Kb[(size_t)row * 512 + o] = f2bf(fmaxf(v, 0.0f));
        } else {
          int h = o >> 6, d = o & 63;
          int b = row >> 11, s = row & 2047;
          Vt[((size_t)(b * 8 + h) * 64 + d) * 2048 + s] = f2bf(v);  // V^T for PV B-frags
        }
      }
}

__global__ __launch_bounds__(256) void proj_gemm(
    const uint16_t* __restrict__ Ob, const uint16_t* __restrict__ Wob,
    const float* __restrict__ bo, float* __restrict__ out) {
  __shared__ __align__(16) uint16_t Alds[128 * 32];
  __shared__ __align__(16) uint16_t Blds[128 * 32];
  f4 acc[4][4] = {};
  const int row0 = blockIdx.y * 128, col0 = blockIdx.x * 128;
  gemm_loop(Ob, Wob, row0, col0, Alds, Blds, acc);
  const int tid = threadIdx.x, w = tid >> 6, lane = tid & 63;
  const int c = lane & 15, quad = lane >> 4;
  const int wm = w >> 1, wn = w & 1;
#pragma unroll
  for (int mi = 0; mi < 4; ++mi)
#pragma unroll
    for (int ni = 0; ni < 4; ++ni)
#pragma unroll
      for (int r = 0; r < 4; ++r) {
        int row = row0 + wm * 64 + mi * 16 + quad * 4 + r;
        int col = col0 + wn * 64 + ni * 16 + c;
        out[(size_t)row * 512 + col] = acc[mi][ni][r] + bo[col];
      }
}

// ---------------------------------------------------------------------------
__global__ __launch_bounds__(256) void ksum_kernel(
    const uint16_t* __restrict__ Kb, float* __restrict__ rq) {
  int i = blockIdx.x * 256 + threadIdx.x;            // 0..32767 = n*8 + h
  const uint16_t* p = Kb + (size_t)i * 64;
  float s = 0.f;
#pragma unroll
  for (int j = 0; j < 64; ++j) s += bf2f(p[j]);
  rq[i] = 1.0f / (s + 1e-6f);
}

// ---------------------------------------------------------------------------
// grid (32 q-tiles, 16 bh), block 256 = 4 waves x 16 query rows.
__global__ __launch_bounds__(256) void attn_kernel(
    const uint16_t* __restrict__ Qb, const uint16_t* __restrict__ Kb,
    const uint16_t* __restrict__ Vt, const float* __restrict__ rq,
    float* __restrict__ attn, uint16_t* __restrict__ Ob) {
  __shared__ __align__(16) uint16_t Klds[64 * 64];     // [key][d]
  __shared__ __align__(16) uint16_t Vlds[64 * 64];     // [d][key]
  __shared__ __align__(16) uint16_t Plds[4][16 * 64];  // per-wave P relayout
  const int tid = threadIdx.x, w = tid >> 6, lane = tid & 63;
  const int c = lane & 15, quad = lane >> 4;
  const int bh = blockIdx.y, b = bh >> 3, h = bh & 7;
  const int n0 = blockIdx.x * 64;
  const int rbase = b * 2048 + n0;
  // Q A-frags (resident for whole kernel): A[m=c][k=quad*8+j]
  const uint16_t* qptr = Qb + (size_t)(rbase + w * 16 + c) * 512 + h * 64 + quad * 8;
  short8 aq0 = *(const short8*)qptr;
  short8 aq1 = *(const short8*)(qptr + 32);
  float rqv[4];
#pragma unroll
  for (int r = 0; r < 4; ++r)
    rqv[r] = rq[(size_t)(rbase + w * 16 + quad * 4 + r) * 8 + h];
  const int srow = lane >> 3, scol = (lane & 7) * 8;   // 1KB chunk: 8 rows x 128B
  const uint16_t* Ksrc = Kb + (size_t)(b * 2048) * 512 + h * 64 + scol;
  const uint16_t* Vsrc = Vt + (size_t)bh * 64 * 2048 + scol;

  // ---- pass 1: row sums of exp(s) ----
  float lsum[4] = {0.f, 0.f, 0.f, 0.f};
  for (int kt = 0; kt < 32; ++kt) {
    __syncthreads();
#pragma unroll
    for (int chh = 0; chh < 2; ++chh) {
      int ch = w * 2 + chh;
      async16(Ksrc + (size_t)(kt * 64 + ch * 8 + srow) * 512, Klds + ch * 512);
    }
    __syncthreads();
#pragma unroll
    for (int ni = 0; ni < 4; ++ni) {
      const uint16_t* kp = &Klds[(ni * 16 + c) * 64 + quad * 8];
      short8 bk0 = *(const short8*)kp;
      short8 bk1 = *(const short8*)(kp + 32);
      f4 s = {};
      s = MFMA(aq0, bk0, s);
      s = MFMA(aq1, bk1, s);
#pragma unroll
      for (int r = 0; r < 4; ++r) lsum[r] += __expf(s[r] * rqv[r]);
    }
  }
  float rli[4];
#pragma unroll
  for (int r = 0; r < 4; ++r) {
    float v = lsum[r];
    v += __shfl_xor(v, 1, 16);
    v += __shfl_xor(v, 2, 16);
    v += __shfl_xor(v, 4, 16);
    v += __shfl_xor(v, 8, 16);
    rli[r] = 1.0f / v;
  }

  // ---- pass 2: write attn, accumulate O = P @ V ----
  f4 oacc[4] = {};
  float* arow = attn + ((size_t)bh * 2048 + n0 + w * 16) * 2048;
  for (int kt = 0; kt < 32; ++kt) {
    __syncthreads();
#pragma unroll
    for (int chh = 0; chh < 2; ++chh) {
      int ch = w * 2 + chh;
      async16(Ksrc + (size_t)(kt * 64 + ch * 8 + srow) * 512, Klds + ch * 512);
      async16(Vsrc + (size_t)(ch * 8 + srow) * 2048 + kt * 64, Vlds + ch * 512);
    }
    __syncthreads();
#pragma unroll
    for (int ni = 0; ni < 4; ++ni) {
      const uint16_t* kp = &Klds[(ni * 16 + c) * 64 + quad * 8];
      short8 bk0 = *(const short8*)kp;
      short8 bk1 = *(const short8*)(kp + 32);
      f4 s = {};
      s = MFMA(aq0, bk0, s);
      s = MFMA(aq1, bk1, s);
#pragma unroll
      for (int r = 0; r < 4; ++r) {
        float p = __expf(s[r] * rqv[r]) * rli[r];
        arow[(size_t)(quad * 4 + r) * 2048 + kt * 64 + ni * 16 + c] = p;
        Plds[w][(quad * 4 + r) * 64 + ni * 16 + c] = f2bf(p);  // C-layout -> LDS
      }
    }
    asm volatile("s_waitcnt lgkmcnt(0)" ::: "memory");  // P writes visible to own wave
#pragma unroll
    for (int ks = 0; ks < 2; ++ks) {
      short8 ap = *(const short8*)&Plds[w][c * 64 + ks * 32 + quad * 8];  // A-layout
#pragma unroll
      for (int nj = 0; nj < 4; ++nj) {
        short8 bvv = *(const short8*)&Vlds[(nj * 16 + c) * 64 + ks * 32 + quad * 8];
        oacc[nj] = MFMA(ap, bvv, oacc[nj]);
      }
    }
  }
#pragma unroll
  for (int nj = 0; nj < 4; ++nj)
#pragma unroll
    for (int r = 0; r < 4; ++r)
      Ob[(size_t)(rbase + w * 16 + quad * 4 + r) * 512 + h * 64 + nj * 16 + c] =
          f2bf(oacc[nj][r]);
}

// ---------------------------------------------------------------------------
extern "C" void kernel_launch(void* const* d_in, const int* in_sizes, int n_in,
                              void* d_out, int out_size, void* d_ws, size_t ws_size,
                              hipStream_t stream) {
  const float* x  = (const float*)d_in[0];
  const float* Wq = (const float*)d_in[1];
  const float* bq = (const float*)d_in[2];
  const float* Wk = (const float*)d_in[3];
  const float* bk = (const float*)d_in[4];
  const float* Wv = (const float*)d_in[5];
  const float* bv = (const float*)d_in[6];
  const float* Wo = (const float*)d_in[7];
  const float* bo = (const float*)d_in[8];

  float* out0 = (float*)d_out;                 // [2,2048,512] fp32
  float* attn = out0 + (size_t)2 * 2048 * 512; // [2,8,2048,2048] fp32

  uint8_t* ws = (uint8_t*)d_ws;
  uint16_t* xb  = (uint16_t*)(ws);              // 4 MB
  uint16_t* W3  = (uint16_t*)(ws + 0x400000);   // 1.5 MB  (Wq|Wk|Wv rows)
  uint16_t* Wob = (uint16_t*)(ws + 0x580000);   // 0.5 MB
  uint16_t* Qb  = (uint16_t*)(ws + 0x600000);   // 4 MB  [4096][512]
  uint16_t* Kb  = (uint16_t*)(ws + 0xA00000);   // 4 MB  [4096][512]
  uint16_t* Vt  = (uint16_t*)(ws + 0xE00000);   // 4 MB  [b][h][64][2048]
  uint16_t* Ob  = (uint16_t*)(ws + 0x1200000);  // 4 MB  [4096][512]
  float*    rq  = (float*)  (ws + 0x1600000);   // 128 KB [4096][8]

  convert_kernel<<<2048, 256, 0, stream>>>(x, Wq, Wk, Wv, Wo, xb, W3, Wob);
  qkv_gemm<<<dim3(12, 32), 256, 0, stream>>>(xb, W3, bq, bk, bv, Qb, Kb, Vt);
  ksum_kernel<<<128, 256, 0, stream>>>(Kb, rq);
  attn_kernel<<<dim3(32, 16), 256, 0, stream>>>(Qb, Kb, Vt, rq, attn, Ob);
  proj_gemm<<<dim3(4, 32), 256, 0, stream>>>(Ob, Wob, bo, out0);
}

// Round 2
// 385.954 us; speedup vs baseline: 1.0598x; 1.0598x over previous
//
#include <hip/hip_runtime.h>
#include <stdint.h>

// ---------------------------------------------------------------------------
// PerformerAttention on MI355X (gfx950), bf16 MFMA pipeline.
// B=2 S=2048 D=512 H=8 dh=64.
// Round 2: XOR-swizzled LDS layouts (conflict-free b128 frag reads),
// fp32 P round-trip + vectorized attn stores, LDS-transposed V epilogue,
// coalesced ksum, XCD-affine attn grid.
// ---------------------------------------------------------------------------

typedef __attribute__((ext_vector_type(8))) short short8;  // 8 x bf16
typedef __attribute__((ext_vector_type(4))) float f4;

#define MFMA(a, b, c) __builtin_amdgcn_mfma_f32_16x16x32_bf16(a, b, c, 0, 0, 0)

struct __align__(8) us4 { uint16_t a, b, c, d; };

__device__ __forceinline__ uint16_t f2bf(float f) {
  union { float f; uint32_t u; } v; v.f = f;
  uint32_t u = v.u;
  return (uint16_t)((u + 0x7fffu + ((u >> 16) & 1u)) >> 16);  // RNE
}
__device__ __forceinline__ float bf2f(uint16_t u) {
  union { uint32_t u; float f; } v; v.u = ((uint32_t)u) << 16; return v.f;
}
__device__ __forceinline__ us4 pack4(float4 v) {
  us4 r; r.a = f2bf(v.x); r.b = f2bf(v.y); r.c = f2bf(v.z); r.d = f2bf(v.w); return r;
}

// async global->LDS, 16B/lane. LDS dest = wave-uniform base + lane*16.
__device__ __forceinline__ void async16(const uint16_t* g, uint16_t* l) {
  __builtin_amdgcn_global_load_lds(
      (const __attribute__((address_space(1))) void*)g,
      (__attribute__((address_space(3))) void*)l, 16, 0, 0);
}

// ---------------------------------------------------------------------------
__global__ __launch_bounds__(256) void convert_kernel(
    const float* __restrict__ x, const float* __restrict__ Wq,
    const float* __restrict__ Wk, const float* __restrict__ Wv,
    const float* __restrict__ Wo, uint16_t* __restrict__ xb,
    uint16_t* __restrict__ W3, uint16_t* __restrict__ Wob) {
  int i = blockIdx.x * 256 + threadIdx.x;
  ((us4*)xb)[i] = pack4(((const float4*)x)[i]);
  if (i < 65536) {
    ((us4*)W3)[i]          = pack4(((const float4*)Wq)[i]);
    ((us4*)W3)[65536 + i]  = pack4(((const float4*)Wk)[i]);
    ((us4*)W3)[131072 + i] = pack4(((const float4*)Wv)[i]);
    ((us4*)Wob)[i]         = pack4(((const float4*)Wo)[i]);
  }
}

// ---------------------------------------------------------------------------
// Shared 128x128 bf16 gemm_bt mainloop: C[row,col] = sum_k A[row,k]*Bt[col,k].
// LDS tile [128 rows][32 k], rows of 4 x 16B chunks. Chunk stored at physical
// slot = chunk ^ (row&3) ^ ((row>>2)&3)  -> b128 frag reads are bank-uniform.
__device__ __forceinline__ void gemm_loop(
    const uint16_t* __restrict__ A, const uint16_t* __restrict__ Bt,
    int row0, int col0, uint16_t* Alds, uint16_t* Blds, f4 (&acc)[4][4]) {
  const int tid = threadIdx.x;
  const int w = tid >> 6, lane = tid & 63;
  const int c = lane & 15, quad = lane >> 4;
  const int wm = w >> 1, wn = w & 1;
  // staging: lane -> row (lane>>2) of 16-row chunk; fetch swizzled 16B slot
  const int srow = lane >> 2;
  const int sslot = ((lane & 3) ^ ((lane >> 2) & 3) ^ ((lane >> 4) & 3)) * 8;
  const uint16_t* Asrc = A + (size_t)(row0 + srow) * 512 + sslot;
  const uint16_t* Bsrc = Bt + (size_t)(col0 + srow) * 512 + sslot;
  // read swizzle for fragment row (..+c): pos = quad ^ (c&3) ^ (c>>2)
  const int posv = (quad ^ (c & 3) ^ (c >> 2)) * 8;
  for (int k0 = 0; k0 < 512; k0 += 32) {
    __syncthreads();
#pragma unroll
    for (int chh = 0; chh < 2; ++chh) {
      int ch = w * 2 + chh;  // 8 chunks of 16 rows
      async16(Asrc + (size_t)ch * 16 * 512 + k0, Alds + ch * 512);
      async16(Bsrc + (size_t)ch * 16 * 512 + k0, Blds + ch * 512);
    }
    __syncthreads();
    short8 af[4], bf[4];
#pragma unroll
    for (int mi = 0; mi < 4; ++mi)
      af[mi] = *(const short8*)&Alds[(wm * 64 + mi * 16 + c) * 32 + posv];
#pragma unroll
    for (int ni = 0; ni < 4; ++ni)
      bf[ni] = *(const short8*)&Blds[(wn * 64 + ni * 16 + c) * 32 + posv];
#pragma unroll
    for (int mi = 0; mi < 4; ++mi)
#pragma unroll
      for (int ni = 0; ni < 4; ++ni)
        acc[mi][ni] = MFMA(af[mi], bf[ni], acc[mi][ni]);
  }
}

// ---------------------------------------------------------------------------
__global__ __launch_bounds__(256) void qkv_gemm(
    const uint16_t* __restrict__ xb, const uint16_t* __restrict__ W3,
    const float* __restrict__ bq, const float* __restrict__ bk,
    const float* __restrict__ bv, uint16_t* __restrict__ Qb,
    uint16_t* __restrict__ Kb, uint16_t* __restrict__ Vt) {
  __shared__ __align__(16) uint16_t Alds[128 * 32];
  __shared__ __align__(16) uint16_t Blds[128 * 32];
  __shared__ __align__(16) uint16_t Ct[128 * 136];  // V transpose staging
  f4 acc[4][4] = {};
  const int row0 = blockIdx.y * 128, col0 = blockIdx.x * 128;
  gemm_loop(xb, W3, row0, col0, Alds, Blds, acc);
  const int tid = threadIdx.x, w = tid >> 6, lane = tid & 63;
  const int c = lane & 15, quad = lane >> 4;
  const int wm = w >> 1, wn = w & 1;
  const int r3 = col0 >> 9;  // 0=Q, 1=K, 2=V (block-uniform)
  if (r3 < 2) {
    const float* bias = (r3 == 0) ? bq : bk;
    uint16_t* dst = (r3 == 0) ? Qb : Kb;
#pragma unroll
    for (int mi = 0; mi < 4; ++mi)
#pragma unroll
      for (int ni = 0; ni < 4; ++ni)
#pragma unroll
        for (int r = 0; r < 4; ++r) {
          int row = row0 + wm * 64 + mi * 16 + quad * 4 + r;
          int col = col0 + wn * 64 + ni * 16 + c;
          int o = col & 511;
          float v = acc[mi][ni][r] + bias[o];
          dst[(size_t)row * 512 + o] = f2bf(fmaxf(v, 0.0f));
        }
  } else {
    // V: bias, convert to bf16 into LDS [s_local][col_local] (+8 pad)
#pragma unroll
    for (int mi = 0; mi < 4; ++mi)
#pragma unroll
      for (int ni = 0; ni < 4; ++ni)
#pragma unroll
        for (int r = 0; r < 4; ++r) {
          int sl = wm * 64 + mi * 16 + quad * 4 + r;
          int cl = wn * 64 + ni * 16 + c;
          int o = (col0 + cl) & 511;
          Ct[sl * 136 + cl] = f2bf(acc[mi][ni][r] + bv[o]);
        }
    __syncthreads();
    // cooperative transposed store: Vt[b*512 + ocol][2048], 16B per store
    const int b = row0 >> 11, s0 = row0 & 2047;
    const int cl = tid >> 1, half = tid & 1;
    const int ocol = (col0 - 1024) + cl;
    uint16_t* vdst = Vt + (size_t)(b * 512 + ocol) * 2048 + s0 + half * 64;
#pragma unroll
    for (int g = 0; g < 8; ++g) {
      union { short8 v; uint16_t e[8]; } o8;
#pragma unroll
      for (int jj = 0; jj < 8; ++jj)
        o8.e[jj] = Ct[(half * 64 + g * 8 + jj) * 136 + cl];
      *(short8*)(vdst + g * 8) = o8.v;
    }
  }
}

__global__ __launch_bounds__(256) void proj_gemm(
    const uint16_t* __restrict__ Ob, const uint16_t* __restrict__ Wob,
    const float* __restrict__ bo, float* __restrict__ out) {
  __shared__ __align__(16) uint16_t Alds[128 * 32];
  __shared__ __align__(16) uint16_t Blds[128 * 32];
  f4 acc[4][4] = {};
  const int row0 = blockIdx.y * 128, col0 = blockIdx.x * 128;
  gemm_loop(Ob, Wob, row0, col0, Alds, Blds, acc);
  const int tid = threadIdx.x, w = tid >> 6, lane = tid & 63;
  const int c = lane & 15, quad = lane >> 4;
  const int wm = w >> 1, wn = w & 1;
#pragma unroll
  for (int mi = 0; mi < 4; ++mi)
#pragma unroll
    for (int ni = 0; ni < 4; ++ni)
#pragma unroll
      for (int r = 0; r < 4; ++r) {
        int row = row0 + wm * 64 + mi * 16 + quad * 4 + r;
        int col = col0 + wn * 64 + ni * 16 + c;
        out[(size_t)row * 512 + col] = acc[mi][ni][r] + bo[col];
      }
}

// ---------------------------------------------------------------------------
// ksum: Kb viewed flat as [32768 rows][64]; rq[row] = 1/(sum+eps).
// 4 lanes per row, 16B vector loads, width-4 shuffle reduce.
__global__ __launch_bounds__(256) void ksum_kernel(
    const uint16_t* __restrict__ Kb, float* __restrict__ rq) {
  int t = blockIdx.x * 256 + threadIdx.x;  // 131072 threads
  int row = t >> 2, part = t & 3;
  const uint4* p = (const uint4*)(Kb + (size_t)row * 64 + part * 16);
  float s = 0.f;
#pragma unroll
  for (int g = 0; g < 2; ++g) {
    union { uint4 u; uint16_t e[8]; } v; v.u = p[g];
#pragma unroll
    for (int j = 0; j < 8; ++j) s += bf2f(v.e[j]);
  }
  s += __shfl_xor(s, 1, 4);
  s += __shfl_xor(s, 2, 4);
  if (part == 0) rq[row] = 1.0f / (s + 1e-6f);
}

// ---------------------------------------------------------------------------
// attn: 1-D grid 512; block = 4 waves x 16 query rows (64-row q-tile).
// K/V LDS tiles 64x64 bf16, 8 x 16B chunks/row stored at slot = chunk^(row&7).
// P tile fp32 per-wave [16][64], 16 x 16B chunks/row at slot = chunk^row.
__global__ __launch_bounds__(256) void attn_kernel(
    const uint16_t* __restrict__ Qb, const uint16_t* __restrict__ Kb,
    const uint16_t* __restrict__ Vt, const float* __restrict__ rq,
    float* __restrict__ attn, uint16_t* __restrict__ Ob) {
  __shared__ __align__(16) uint16_t Klds[64 * 64];
  __shared__ __align__(16) uint16_t Vlds[64 * 64];
  __shared__ __align__(16) float Pw[4][16 * 64];
  const int tid = threadIdx.x, w = tid >> 6, lane = tid & 63;
  const int c = lane & 15, quad = lane >> 4, c7 = c & 7;
  // XCD-affine decode: 2 heads per XCD slot, q-tiles cluster with their head
  const int bid = blockIdx.x;
  const int bh = (bid & 7) * 2 + ((bid >> 3) & 1);
  const int qt = bid >> 4;  // 0..31
  const int b = bh >> 3, h = bh & 7;
  const int n0 = qt * 64;
  const int rbase = b * 2048 + n0;
  // Q A-frags, resident: A[m=c][k=quad*8+j]
  const uint16_t* qptr = Qb + (size_t)(rbase + w * 16 + c) * 512 + h * 64 + quad * 8;
  short8 aq0 = *(const short8*)qptr;
  short8 aq1 = *(const short8*)(qptr + 32);
  float rqv[4];
#pragma unroll
  for (int r = 0; r < 4; ++r)
    rqv[r] = rq[(size_t)(rbase + w * 16 + quad * 4 + r) * 8 + h];
  // staging: lane -> row lane>>3 of 8-row chunk, swizzled 16B slot
  const int vsrow = lane >> 3;
  const int vslot = ((lane & 7) ^ vsrow) * 8;
  const uint16_t* Ksrc = Kb + (size_t)(b * 2048) * 512 + h * 64 + vslot;
  const uint16_t* Vsrc = Vt + (size_t)(bh * 64) * 2048 + vslot;

  // ---- pass 1: row sums of exp ----
  float lsum[4] = {0.f, 0.f, 0.f, 0.f};
  for (int kt = 0; kt < 32; ++kt) {
    __syncthreads();
#pragma unroll
    for (int chh = 0; chh < 2; ++chh) {
      int ch = w * 2 + chh;
      async16(Ksrc + (size_t)(kt * 64 + ch * 8 + vsrow) * 512, Klds + ch * 512);
    }
    __syncthreads();
#pragma unroll
    for (int ni = 0; ni < 4; ++ni) {
      const uint16_t* kp = &Klds[(ni * 16 + c) * 64];
      short8 bk0 = *(const short8*)(kp + ((quad ^ c7) * 8));
      short8 bk1 = *(const short8*)(kp + (((quad + 4) ^ c7) * 8));
      f4 s = {};
      s = MFMA(aq0, bk0, s);
      s = MFMA(aq1, bk1, s);
#pragma unroll
      for (int r = 0; r < 4; ++r) lsum[r] += __expf(s[r] * rqv[r]);
    }
  }
  float rli[4];
#pragma unroll
  for (int r = 0; r < 4; ++r) {
    float v = lsum[r];
    v += __shfl_xor(v, 1, 16);
    v += __shfl_xor(v, 2, 16);
    v += __shfl_xor(v, 4, 16);
    v += __shfl_xor(v, 8, 16);
    rli[r] = 1.0f / v;
  }

  // ---- pass 2: write attn (vectorized), accumulate O = P @ V ----
  f4 oacc[4] = {};
  float* arowc = attn + ((size_t)bh * 2048 + n0 + w * 16 + c) * 2048;
  float* Pme = Pw[w];
  for (int kt = 0; kt < 32; ++kt) {
    __syncthreads();
#pragma unroll
    for (int chh = 0; chh < 2; ++chh) {
      int ch = w * 2 + chh;
      async16(Ksrc + (size_t)(kt * 64 + ch * 8 + vsrow) * 512, Klds + ch * 512);
      async16(Vsrc + (size_t)(ch * 8 + vsrow) * 2048 + kt * 64, Vlds + ch * 512);
    }
    __syncthreads();
#pragma unroll
    for (int ni = 0; ni < 4; ++ni) {
      const uint16_t* kp = &Klds[(ni * 16 + c) * 64];
      short8 bk0 = *(const short8*)(kp + ((quad ^ c7) * 8));
      short8 bk1 = *(const short8*)(kp + (((quad + 4) ^ c7) * 8));
      f4 s = {};
      s = MFMA(aq0, bk0, s);
      s = MFMA(aq1, bk1, s);
#pragma unroll
      for (int r = 0; r < 4; ++r) {
        int rowp = quad * 4 + r;
        float p = __expf(s[r] * rqv[r]) * rli[r];
        Pme[rowp * 64 + (((ni * 4 + (c >> 2)) ^ rowp) * 4) + (c & 3)] = p;
      }
    }
    asm volatile("s_waitcnt lgkmcnt(0)" ::: "memory");  // wave's P visible
#pragma unroll
    for (int ks = 0; ks < 2; ++ks) {
      int ch0 = ks * 8 + quad * 2;
      f4 p0 = *(const f4*)&Pme[c * 64 + ((ch0 ^ c) * 4)];
      f4 p1 = *(const f4*)&Pme[c * 64 + (((ch0 + 1) ^ c) * 4)];
      *(f4*)&arowc[kt * 64 + ch0 * 4] = p0;
      *(f4*)&arowc[kt * 64 + ch0 * 4 + 4] = p1;
      union { short8 v; uint16_t e[8]; } ap;
#pragma unroll
      for (int i = 0; i < 4; ++i) { ap.e[i] = f2bf(p0[i]); ap.e[4 + i] = f2bf(p1[i]); }
#pragma unroll
      for (int nj = 0; nj < 4; ++nj) {
        short8 bvv = *(const short8*)&Vlds[(nj * 16 + c) * 64 +
                                           (((ks * 4 + quad) ^ c7) * 8)];
        oacc[nj] = MFMA(ap.v, bvv, oacc[nj]);
      }
    }
  }
#pragma unroll
  for (int nj = 0; nj < 4; ++nj)
#pragma unroll
    for (int r = 0; r < 4; ++r)
      Ob[(size_t)(rbase + w * 16 + quad * 4 + r) * 512 + h * 64 + nj * 16 + c] =
          f2bf(oacc[nj][r]);
}

// ---------------------------------------------------------------------------
extern "C" void kernel_launch(void* const* d_in, const int* in_sizes, int n_in,
                              void* d_out, int out_size, void* d_ws, size_t ws_size,
                              hipStream_t stream) {
  const float* x  = (const float*)d_in[0];
  const float* Wq = (const float*)d_in[1];
  const float* bq = (const float*)d_in[2];
  const float* Wk = (const float*)d_in[3];
  const float* bk = (const float*)d_in[4];
  const float* Wv = (const float*)d_in[5];
  const float* bv = (const float*)d_in[6];
  const float* Wo = (const float*)d_in[7];
  const float* bo = (const float*)d_in[8];

  float* out0 = (float*)d_out;                  // [2,2048,512] fp32
  float* attn = out0 + (size_t)2 * 2048 * 512;  // [2,8,2048,2048] fp32

  uint8_t* ws = (uint8_t*)d_ws;
  uint16_t* xb  = (uint16_t*)(ws);              // 4 MB
  uint16_t* W3  = (uint16_t*)(ws + 0x400000);   // 1.5 MB (Wq|Wk|Wv rows)
  uint16_t* Wob = (uint16_t*)(ws + 0x580000);   // 0.5 MB
  uint16_t* Qb  = (uint16_t*)(ws + 0x600000);   // 4 MB [4096][512]
  uint16_t* Kb  = (uint16_t*)(ws + 0xA00000);   // 4 MB [4096][512]
  uint16_t* Vt  = (uint16_t*)(ws + 0xE00000);   // 4 MB [b*512+h*64+d][2048]
  uint16_t* Ob  = (uint16_t*)(ws + 0x1200000);  // 4 MB [4096][512]
  float*    rq  = (float*)  (ws + 0x1600000);   // 128 KB [4096*8]

  convert_kernel<<<2048, 256, 0, stream>>>(x, Wq, Wk, Wv, Wo, xb, W3, Wob);
  qkv_gemm<<<dim3(12, 32), 256, 0, stream>>>(xb, W3, bq, bk, bv, Qb, Kb, Vt);
  ksum_kernel<<<512, 256, 0, stream>>>(Kb, rq);
  attn_kernel<<<512, 256, 0, stream>>>(Qb, Kb, Vt, rq, attn, Ob);
  proj_gemm<<<dim3(4, 32), 256, 0, stream>>>(Ob, Wob, bo, out0);
}